// Round 1
// baseline (503.729 us; speedup 1.0000x reference)
//
#include <hip/hip_runtime.h>
#include <hip/hip_bf16.h>
#include <math.h>

#define B_ 4
#define T_ 2048
#define C_ 1024
#define H_ 16
#define D_ 64
#define BT (B_*T_)
#define BH (B_*H_)

typedef __bf16 bf16x8 __attribute__((ext_vector_type(8)));
typedef float f32x4 __attribute__((ext_vector_type(4)));
typedef unsigned short u16;
typedef u16 u16x8 __attribute__((ext_vector_type(8)));

__device__ __forceinline__ u16 f2b(float f) {
    union { float f; unsigned u; } v; v.f = f;
    unsigned r = v.u + 0x7fffu + ((v.u >> 16) & 1u);
    return (u16)(r >> 16);
}

// ---------------- cast fp32 -> bf16 (n divisible by 1024) ----------------
__global__ __launch_bounds__(256) void cast_f32_bf16(const float* __restrict__ in,
                                                     u16* __restrict__ out) {
    int g = blockIdx.x * 256 + threadIdx.x;
    float4 x = ((const float4*)in)[g];
    ushort4 o;
    o.x = f2b(x.x); o.y = f2b(x.y); o.z = f2b(x.z); o.w = f2b(x.w);
    ((ushort4*)out)[g] = o;
}

// ------------- Wq/Wk/Wv [H,C,D] fp32 -> [3,H,D,C] bf16 -------------------
__global__ __launch_bounds__(256) void transpose_w(const float* __restrict__ Wq,
                                                   const float* __restrict__ Wk,
                                                   const float* __restrict__ Wv,
                                                   u16* __restrict__ out) {
    __shared__ u16 lds[64][72];
    int cb = blockIdx.x, h = blockIdx.y, w = blockIdx.z;
    const float* W = (w == 0) ? Wq : (w == 1) ? Wk : Wv;
    int tid = threadIdx.x;
    int c0 = cb * 64;
    {
        int col = (tid & 15) * 4;
        for (int cc = 0; cc < 4; ++cc) {
            int r = (tid >> 4) + cc * 16;
            float4 x = *(const float4*)&W[(size_t)(h * C_ + c0 + r) * D_ + col];
            lds[r][col + 0] = f2b(x.x); lds[r][col + 1] = f2b(x.y);
            lds[r][col + 2] = f2b(x.z); lds[r][col + 3] = f2b(x.w);
        }
    }
    __syncthreads();
    {
        int tcol = (tid & 7) * 8;
        for (int cc = 0; cc < 2; ++cc) {
            int d = (tid >> 3) + cc * 32;
            u16x8 t;
            for (int j = 0; j < 8; ++j) t[j] = lds[tcol + j][d];
            *(u16x8*)&out[(((size_t)(w * H_ + h) * D_ + d) * C_) + c0 + tcol] = t;
        }
    }
}

// ------- batched QKV GEMM: x[8192,1024] x Wt[w][64,1024] -> q/k/v [BH,T,D] -------
__global__ __launch_bounds__(256) void qkv_gemm(const u16* __restrict__ xbf,
                                                const u16* __restrict__ wt,
                                                u16* __restrict__ q, u16* __restrict__ k,
                                                u16* __restrict__ v) {
    __shared__ u16 Al[128][72];
    __shared__ u16 Bl[64][72];
    int mb = blockIdx.x, w = blockIdx.y;
    int wsel = w >> 4, h = w & 15;
    u16* outp = (wsel == 0) ? q : (wsel == 1) ? k : v;
    const u16* wrow = wt + (size_t)w * D_ * C_;
    int tid = threadIdx.x, wid = tid >> 6, lane = tid & 63, l15 = lane & 15, quad = lane >> 4;
    f32x4 acc[2][4];
    for (int i = 0; i < 2; ++i) for (int j = 0; j < 4; ++j) acc[i][j] = (f32x4){0.f, 0.f, 0.f, 0.f};
    int scol = (tid & 7) * 8, srow = tid >> 3;
    for (int k0 = 0; k0 < C_; k0 += 64) {
        for (int cc = 0; cc < 4; ++cc) {
            int r = srow + cc * 32;
            *(u16x8*)&Al[r][scol] = *(const u16x8*)&xbf[(size_t)(mb * 128 + r) * C_ + k0 + scol];
        }
        for (int cc = 0; cc < 2; ++cc) {
            int r = srow + cc * 32;
            *(u16x8*)&Bl[r][scol] = *(const u16x8*)&wrow[(size_t)r * C_ + k0 + scol];
        }
        __syncthreads();
        for (int ks = 0; ks < 2; ++ks) {
            bf16x8 a0 = *(const bf16x8*)&Al[wid * 32 + l15][ks * 32 + quad * 8];
            bf16x8 a1 = *(const bf16x8*)&Al[wid * 32 + 16 + l15][ks * 32 + quad * 8];
            for (int nt = 0; nt < 4; ++nt) {
                bf16x8 b = *(const bf16x8*)&Bl[nt * 16 + l15][ks * 32 + quad * 8];
                acc[0][nt] = __builtin_amdgcn_mfma_f32_16x16x32_bf16(a0, b, acc[0][nt], 0, 0, 0);
                acc[1][nt] = __builtin_amdgcn_mfma_f32_16x16x32_bf16(a1, b, acc[1][nt], 0, 0, 0);
            }
        }
        __syncthreads();
    }
    for (int ms = 0; ms < 2; ++ms)
        for (int nt = 0; nt < 4; ++nt)
            for (int r = 0; r < 4; ++r) {
                int m = mb * 128 + wid * 32 + ms * 16 + quad * 4 + r;
                int b = m >> 11, t = m & (T_ - 1);
                int n = nt * 16 + l15;
                outp[((size_t)(b * H_ + h) * T_ + t) * D_ + n] = f2b(acc[ms][nt][r]);
            }
}

// ---------------- V [BH,T,D] -> Vt [BH,D,T] (bf16) ----------------
__global__ __launch_bounds__(256) void vtrans(const u16* __restrict__ v, u16* __restrict__ vt) {
    __shared__ u16 lds[64][72];
    int tb = blockIdx.x, bh = blockIdx.y;
    int t0 = tb * 64, tid = threadIdx.x;
    int col = (tid & 7) * 8;
    for (int cc = 0; cc < 2; ++cc) {
        int r = (tid >> 3) + cc * 32;
        *(u16x8*)&lds[r][col] = *(const u16x8*)&v[((size_t)bh * T_ + t0 + r) * D_ + col];
    }
    __syncthreads();
    for (int cc = 0; cc < 2; ++cc) {
        int d = (tid >> 3) + cc * 32;
        u16x8 t;
        for (int j = 0; j < 8; ++j) t[j] = lds[col + j][d];
        *(u16x8*)&vt[((size_t)bh * D_ + d) * T_ + t0 + col] = t;
    }
}

// ---------------- flash attention: q,k [BH,T,D], vt [BH,D,T] -> att [B*T, C] bf16 ----------------
__global__ __launch_bounds__(256) void attn(const u16* __restrict__ q, const u16* __restrict__ kk,
                                            const u16* __restrict__ vt, u16* __restrict__ att) {
    __shared__ u16 Kl[64][72];
    __shared__ u16 Vl[64][72];
    __shared__ u16 Pl[4][16][72];
    int qt = blockIdx.x, bh = blockIdx.y;
    int b = bh >> 4, h = bh & 15;
    int q0 = qt * 64;
    int tid = threadIdx.x, wid = tid >> 6, lane = tid & 63, l15 = lane & 15, quad = lane >> 4;
    const u16* qp = q + ((size_t)bh * T_ + q0 + wid * 16 + l15) * D_;
    bf16x8 aq0 = *(const bf16x8*)&qp[quad * 8];
    bf16x8 aq1 = *(const bf16x8*)&qp[32 + quad * 8];
    float mrow[4], lrow[4];
    f32x4 o[4];
    for (int r = 0; r < 4; ++r) { mrow[r] = -INFINITY; lrow[r] = 0.f; }
    for (int nt = 0; nt < 4; ++nt) o[nt] = (f32x4){0.f, 0.f, 0.f, 0.f};
    int scol = (tid & 7) * 8, srow = tid >> 3;
    const float scale = 0.03125f;  // C^-0.5
    for (int kt = 0; kt <= qt; ++kt) {
        int k0 = kt * 64;
        for (int cc = 0; cc < 2; ++cc) {
            int r = srow + cc * 32;
            *(u16x8*)&Kl[r][scol] = *(const u16x8*)&kk[((size_t)bh * T_ + k0 + r) * D_ + scol];
            *(u16x8*)&Vl[r][scol] = *(const u16x8*)&vt[((size_t)bh * D_ + r) * T_ + k0 + scol];
        }
        __syncthreads();
        f32x4 s[4];
        for (int nt = 0; nt < 4; ++nt) s[nt] = (f32x4){0.f, 0.f, 0.f, 0.f};
        for (int ks = 0; ks < 2; ++ks) {
            bf16x8 a = ks ? aq1 : aq0;
            for (int nt = 0; nt < 4; ++nt) {
                bf16x8 bb = *(const bf16x8*)&Kl[nt * 16 + l15][ks * 32 + quad * 8];
                s[nt] = __builtin_amdgcn_mfma_f32_16x16x32_bf16(a, bb, s[nt], 0, 0, 0);
            }
        }
        bool diag = (kt == qt);
        for (int nt = 0; nt < 4; ++nt)
            for (int r = 0; r < 4; ++r) {
                float sv = s[nt][r] * scale;
                if (diag && (nt * 16 + l15 > wid * 16 + quad * 4 + r)) sv = -INFINITY;
                s[nt][r] = sv;
            }
        float alpha[4];
        for (int r = 0; r < 4; ++r) {
            float vmax = fmaxf(fmaxf(s[0][r], s[1][r]), fmaxf(s[2][r], s[3][r]));
            vmax = fmaxf(vmax, __shfl_xor(vmax, 1));
            vmax = fmaxf(vmax, __shfl_xor(vmax, 2));
            vmax = fmaxf(vmax, __shfl_xor(vmax, 4));
            vmax = fmaxf(vmax, __shfl_xor(vmax, 8));
            float mnew = fmaxf(mrow[r], vmax);
            alpha[r] = __expf(mrow[r] - mnew);
            mrow[r] = mnew;
        }
        for (int nt = 0; nt < 4; ++nt)
            for (int r = 0; r < 4; ++r)
                s[nt][r] = __expf(s[nt][r] - mrow[r]);
        for (int r = 0; r < 4; ++r) {
            float sum = s[0][r] + s[1][r] + s[2][r] + s[3][r];
            sum += __shfl_xor(sum, 1);
            sum += __shfl_xor(sum, 2);
            sum += __shfl_xor(sum, 4);
            sum += __shfl_xor(sum, 8);
            lrow[r] = lrow[r] * alpha[r] + sum;
        }
        for (int nt = 0; nt < 4; ++nt)
            for (int r = 0; r < 4; ++r)
                o[nt][r] *= alpha[r];
        for (int nt = 0; nt < 4; ++nt)
            for (int r = 0; r < 4; ++r)
                Pl[wid][quad * 4 + r][nt * 16 + l15] = f2b(s[nt][r]);
        __syncthreads();
        for (int ks = 0; ks < 2; ++ks) {
            bf16x8 ap = *(const bf16x8*)&Pl[wid][l15][ks * 32 + quad * 8];
            for (int nt = 0; nt < 4; ++nt) {
                bf16x8 bb = *(const bf16x8*)&Vl[nt * 16 + l15][ks * 32 + quad * 8];
                o[nt] = __builtin_amdgcn_mfma_f32_16x16x32_bf16(ap, bb, o[nt], 0, 0, 0);
            }
        }
        __syncthreads();
    }
    for (int nt = 0; nt < 4; ++nt)
        for (int r = 0; r < 4; ++r) {
            int t = q0 + wid * 16 + quad * 4 + r;
            float val = o[nt][r] / lrow[r];
            att[(size_t)(b * T_ + t) * C_ + h * D_ + nt * 16 + l15] = f2b(val);
        }
}

// ---------------- out proj: att [8192,1024] x Wo^T + bo -> fp32 out ----------------
__global__ __launch_bounds__(256) void out_gemm(const u16* __restrict__ att,
                                                const u16* __restrict__ wo,
                                                const float* __restrict__ bo,
                                                float* __restrict__ out) {
    __shared__ u16 Al[128][72];
    __shared__ u16 Bl[64][72];
    int mb = blockIdx.x, nb = blockIdx.y;
    int tid = threadIdx.x, wid = tid >> 6, lane = tid & 63, l15 = lane & 15, quad = lane >> 4;
    f32x4 acc[2][4];
    for (int i = 0; i < 2; ++i) for (int j = 0; j < 4; ++j) acc[i][j] = (f32x4){0.f, 0.f, 0.f, 0.f};
    int scol = (tid & 7) * 8, srow = tid >> 3;
    for (int k0 = 0; k0 < C_; k0 += 64) {
        for (int cc = 0; cc < 4; ++cc) {
            int r = srow + cc * 32;
            *(u16x8*)&Al[r][scol] = *(const u16x8*)&att[(size_t)(mb * 128 + r) * C_ + k0 + scol];
        }
        for (int cc = 0; cc < 2; ++cc) {
            int r = srow + cc * 32;
            *(u16x8*)&Bl[r][scol] = *(const u16x8*)&wo[(size_t)(nb * 64 + r) * C_ + k0 + scol];
        }
        __syncthreads();
        for (int ks = 0; ks < 2; ++ks) {
            bf16x8 a0 = *(const bf16x8*)&Al[wid * 32 + l15][ks * 32 + quad * 8];
            bf16x8 a1 = *(const bf16x8*)&Al[wid * 32 + 16 + l15][ks * 32 + quad * 8];
            for (int nt = 0; nt < 4; ++nt) {
                bf16x8 b = *(const bf16x8*)&Bl[nt * 16 + l15][ks * 32 + quad * 8];
                acc[0][nt] = __builtin_amdgcn_mfma_f32_16x16x32_bf16(a0, b, acc[0][nt], 0, 0, 0);
                acc[1][nt] = __builtin_amdgcn_mfma_f32_16x16x32_bf16(a1, b, acc[1][nt], 0, 0, 0);
            }
        }
        __syncthreads();
    }
    for (int ms = 0; ms < 2; ++ms)
        for (int nt = 0; nt < 4; ++nt) {
            int n = nb * 64 + nt * 16 + l15;
            float bias = bo[n];
            for (int r = 0; r < 4; ++r) {
                int m = mb * 128 + wid * 32 + ms * 16 + quad * 4 + r;
                out[(size_t)m * C_ + n] = acc[ms][nt][r] + bias;
            }
        }
}

extern "C" void kernel_launch(void* const* d_in, const int* in_sizes, int n_in,
                              void* d_out, int out_size, void* d_ws, size_t ws_size,
                              hipStream_t stream) {
    const float* x  = (const float*)d_in[0];
    const float* Wq = (const float*)d_in[1];
    const float* Wk = (const float*)d_in[2];
    const float* Wv = (const float*)d_in[3];
    const float* Wo = (const float*)d_in[4];
    const float* bo = (const float*)d_in[5];
    float* out = (float*)d_out;
    char* ws = (char*)d_ws;
    // workspace layout (bytes), total 104 MB
    u16* xbf  = (u16*)(ws + (size_t)0);           // 16 MB  x as bf16 [8192,1024]
    u16* wt   = (u16*)(ws + ((size_t)16 << 20));  //  6 MB  Wq/Wk/Wv as [3,H,D,C] bf16
    u16* wobf = (u16*)(ws + ((size_t)22 << 20));  //  2 MB  Wo bf16 [1024,1024]
    u16* qb   = (u16*)(ws + ((size_t)24 << 20));  // 16 MB  q [BH,T,D]
    u16* kb   = (u16*)(ws + ((size_t)40 << 20));  // 16 MB  k [BH,T,D]
    u16* vb   = (u16*)(ws + ((size_t)56 << 20));  // 16 MB  v [BH,T,D]
    u16* vtb  = (u16*)(ws + ((size_t)72 << 20));  // 16 MB  v^T [BH,D,T]
    u16* attb = (u16*)(ws + ((size_t)88 << 20));  // 16 MB  att out [B*T,C]

    hipLaunchKernelGGL(cast_f32_bf16, dim3(BT * C_ / 1024), dim3(256), 0, stream, x, xbf);
    hipLaunchKernelGGL(cast_f32_bf16, dim3(C_ * C_ / 1024), dim3(256), 0, stream, Wo, wobf);
    hipLaunchKernelGGL(transpose_w, dim3(C_ / 64, H_, 3), dim3(256), 0, stream, Wq, Wk, Wv, wt);
    hipLaunchKernelGGL(qkv_gemm, dim3(BT / 128, 48), dim3(256), 0, stream, xbf, wt, qb, kb, vb);
    hipLaunchKernelGGL(vtrans, dim3(T_ / 64, BH), dim3(256), 0, stream, vb, vtb);
    hipLaunchKernelGGL(attn, dim3(T_ / 64, BH), dim3(256), 0, stream, qb, kb, vtb, attb);
    hipLaunchKernelGGL(out_gemm, dim3(BT / 128, C_ / 64), dim3(256), 0, stream, attb, wobf, bo, out);
}

// Round 2
// 317.265 us; speedup vs baseline: 1.5877x; 1.5877x over previous
//
#include <hip/hip_runtime.h>
#include <hip/hip_bf16.h>
#include <math.h>

#define B_ 4
#define T_ 2048
#define C_ 1024
#define H_ 16
#define D_ 64
#define BT (B_*T_)
#define BH (B_*H_)

typedef __bf16 bf16x8 __attribute__((ext_vector_type(8)));
typedef __bf16 bf16x4 __attribute__((ext_vector_type(4)));
typedef float f32x4 __attribute__((ext_vector_type(4)));
typedef unsigned short u16;
typedef u16 u16x8 __attribute__((ext_vector_type(8)));

__device__ __forceinline__ u16 f2b(float f) {
    union { float f; unsigned u; } v; v.f = f;
    unsigned r = v.u + 0x7fffu + ((v.u >> 16) & 1u);
    return (u16)(r >> 16);
}

// ---------------- cast fp32 -> bf16 (n divisible by 1024) ----------------
__global__ __launch_bounds__(256) void cast_f32_bf16(const float* __restrict__ in,
                                                     u16* __restrict__ out) {
    int g = blockIdx.x * 256 + threadIdx.x;
    float4 x = ((const float4*)in)[g];
    ushort4 o;
    o.x = f2b(x.x); o.y = f2b(x.y); o.z = f2b(x.z); o.w = f2b(x.w);
    ((ushort4*)out)[g] = o;
}

// ------------- Wq/Wk/Wv [H,C,D] fp32 -> [3,H,D,C] bf16 (= [3072,1024]) ----
__global__ __launch_bounds__(256) void transpose_w(const float* __restrict__ Wq,
                                                   const float* __restrict__ Wk,
                                                   const float* __restrict__ Wv,
                                                   u16* __restrict__ out) {
    __shared__ u16 lds[64][72];
    int cb = blockIdx.x, h = blockIdx.y, w = blockIdx.z;
    const float* W = (w == 0) ? Wq : (w == 1) ? Wk : Wv;
    int tid = threadIdx.x;
    int c0 = cb * 64;
    {
        int col = (tid & 15) * 4;
        for (int cc = 0; cc < 4; ++cc) {
            int r = (tid >> 4) + cc * 16;
            float4 x = *(const float4*)&W[(size_t)(h * C_ + c0 + r) * D_ + col];
            lds[r][col + 0] = f2b(x.x); lds[r][col + 1] = f2b(x.y);
            lds[r][col + 2] = f2b(x.z); lds[r][col + 3] = f2b(x.w);
        }
    }
    __syncthreads();
    {
        int tcol = (tid & 7) * 8;
        for (int cc = 0; cc < 2; ++cc) {
            int d = (tid >> 3) + cc * 32;
            u16x8 t;
            for (int j = 0; j < 8; ++j) t[j] = lds[tcol + j][d];
            *(u16x8*)&out[(((size_t)(w * H_ + h) * D_ + d) * C_) + c0 + tcol] = t;
        }
    }
}

// ------- fused QKV GEMM: x[8192,1024] x wt[3072,1024]^T -> q/k/v [BH,T,D] -------
// 128x128 block tile, 4 waves, each wave 64x64 (4x4 acc).
__global__ __launch_bounds__(256) void qkv_gemm(const u16* __restrict__ xbf,
                                                const u16* __restrict__ wt,
                                                u16* __restrict__ q, u16* __restrict__ k,
                                                u16* __restrict__ v) {
    __shared__ u16 Al[128][72];
    __shared__ u16 Bl[128][72];
    int mb = blockIdx.x, nb = blockIdx.y;
    int tid = threadIdx.x, wid = tid >> 6, lane = tid & 63, l15 = lane & 15, quad = lane >> 4;
    int rowh = (wid & 1) * 64, colh = (wid >> 1) * 64;
    f32x4 acc[4][4];
    #pragma unroll
    for (int i = 0; i < 4; ++i)
        #pragma unroll
        for (int j = 0; j < 4; ++j) acc[i][j] = (f32x4){0.f, 0.f, 0.f, 0.f};
    int scol = (tid & 7) * 8, srow = tid >> 3;
    for (int k0 = 0; k0 < C_; k0 += 64) {
        #pragma unroll
        for (int cc = 0; cc < 4; ++cc) {
            int r = srow + cc * 32;
            *(u16x8*)&Al[r][scol] = *(const u16x8*)&xbf[(size_t)(mb * 128 + r) * C_ + k0 + scol];
            *(u16x8*)&Bl[r][scol] = *(const u16x8*)&wt[(size_t)(nb * 128 + r) * C_ + k0 + scol];
        }
        __syncthreads();
        #pragma unroll
        for (int ks = 0; ks < 2; ++ks) {
            bf16x8 af[4], bf[4];
            #pragma unroll
            for (int mt = 0; mt < 4; ++mt)
                af[mt] = *(const bf16x8*)&Al[rowh + mt * 16 + l15][ks * 32 + quad * 8];
            #pragma unroll
            for (int nt = 0; nt < 4; ++nt)
                bf[nt] = *(const bf16x8*)&Bl[colh + nt * 16 + l15][ks * 32 + quad * 8];
            #pragma unroll
            for (int mt = 0; mt < 4; ++mt)
                #pragma unroll
                for (int nt = 0; nt < 4; ++nt)
                    acc[mt][nt] = __builtin_amdgcn_mfma_f32_16x16x32_bf16(af[mt], bf[nt], acc[mt][nt], 0, 0, 0);
        }
        __syncthreads();
    }
    #pragma unroll
    for (int nt = 0; nt < 4; ++nt) {
        int n0 = nb * 128 + colh + nt * 16;
        int wsel = n0 >> 10, hh = (n0 >> 6) & 15, d0 = n0 & 63;
        u16* op = (wsel == 0) ? q : (wsel == 1) ? k : v;
        #pragma unroll
        for (int mt = 0; mt < 4; ++mt)
            #pragma unroll
            for (int r = 0; r < 4; ++r) {
                int m = mb * 128 + rowh + mt * 16 + quad * 4 + r;
                int bb = m >> 11, tt = m & (T_ - 1);
                op[((size_t)(bb * H_ + hh) * T_ + tt) * D_ + d0 + l15] = f2b(acc[mt][nt][r]);
            }
    }
}

// ---------------- V [BH,T,D] -> Vt [BH,D,T] (bf16) ----------------
__global__ __launch_bounds__(256) void vtrans(const u16* __restrict__ v, u16* __restrict__ vt) {
    __shared__ u16 lds[64][72];
    int tb = blockIdx.x, bh = blockIdx.y;
    int t0 = tb * 64, tid = threadIdx.x;
    int col = (tid & 7) * 8;
    for (int cc = 0; cc < 2; ++cc) {
        int r = (tid >> 3) + cc * 32;
        *(u16x8*)&lds[r][col] = *(const u16x8*)&v[((size_t)bh * T_ + t0 + r) * D_ + col];
    }
    __syncthreads();
    for (int cc = 0; cc < 2; ++cc) {
        int d = (tid >> 3) + cc * 32;
        u16x8 t;
        for (int j = 0; j < 8; ++j) t[j] = lds[col + j][d];
        *(u16x8*)&vt[((size_t)bh * D_ + d) * T_ + t0 + col] = t;
    }
}

// -------- barrier-free flash attention (S^T / O^T form) -------------------
// Block = 4 waves. Wave w owns 32 Q rows; block covers 128-row chunk pair
// (c, 15-c) -> exactly 33/34 KV-tile units per wave, uniform across blocks.
// No __syncthreads anywhere: K/V/Q frags load direct from global, P round-
// trips through wave-private LDS.
__global__ __launch_bounds__(256) void attn(const u16* __restrict__ q, const u16* __restrict__ kk,
                                            const u16* __restrict__ vt, u16* __restrict__ att) {
    __shared__ u16 Pl[4][32][72];
    int p = blockIdx.x, bh = blockIdx.y;
    int b = bh >> 4, h = bh & 15;
    int tid = threadIdx.x, wid = tid >> 6, lane = tid & 63, l15 = lane & 15, quad = lane >> 4;
    const float scale2 = 0.04508422f;  // C^-0.5 * log2(e)
    const u16* qbase = q + (size_t)bh * T_ * D_;
    const u16* kbase = kk + (size_t)bh * T_ * D_;
    const u16* vbase = vt + (size_t)bh * D_ * T_;
    u16* pw = &Pl[wid][0][0];
    bf16x8 ones;
    #pragma unroll
    for (int j = 0; j < 8; ++j) ones[j] = (__bf16)1.0f;

    for (int ci = 0; ci < 2; ++ci) {
        int c = ci ? (15 - p) : p;
        int R0 = c * 128 + wid * 32;
        // Q^T B-frags: B[k=d][n=qrow]
        bf16x8 bq[2][2];
        #pragma unroll
        for (int qt = 0; qt < 2; ++qt)
            #pragma unroll
            for (int kd = 0; kd < 2; ++kd)
                bq[qt][kd] = *(const bf16x8*)&qbase[(size_t)(R0 + qt * 16 + l15) * D_ + kd * 32 + quad * 8];
        f32x4 o[4][2];
        f32x4 lacc[2];
        float m2[2] = {-INFINITY, -INFINITY};
        #pragma unroll
        for (int dt = 0; dt < 4; ++dt)
            #pragma unroll
            for (int qt = 0; qt < 2; ++qt) o[dt][qt] = (f32x4){0.f, 0.f, 0.f, 0.f};
        lacc[0] = (f32x4){0.f, 0.f, 0.f, 0.f};
        lacc[1] = (f32x4){0.f, 0.f, 0.f, 0.f};
        int ktmax = R0 >> 6;
        for (int kt = 0; kt <= ktmax; ++kt) {
            int k0 = kt * 64;
            // K A-frags: A[m=kv][k=d]
            bf16x8 ak[4][2];
            #pragma unroll
            for (int kvt = 0; kvt < 4; ++kvt)
                #pragma unroll
                for (int kd = 0; kd < 2; ++kd)
                    ak[kvt][kd] = *(const bf16x8*)&kbase[(size_t)(k0 + kvt * 16 + l15) * D_ + kd * 32 + quad * 8];
            // V^T A-frags: A[m=d][k=kv]  (needed only after softmax; issued early)
            bf16x8 av[4][2];
            #pragma unroll
            for (int dt = 0; dt < 4; ++dt)
                #pragma unroll
                for (int ks = 0; ks < 2; ++ks)
                    av[dt][ks] = *(const bf16x8*)&vbase[(size_t)(dt * 16 + l15) * T_ + k0 + ks * 32 + quad * 8];
            // S^T = K . Q^T : C col = qrow(l15), row = kv(quad*4+r)
            f32x4 s[4][2];
            #pragma unroll
            for (int kvt = 0; kvt < 4; ++kvt)
                #pragma unroll
                for (int qt = 0; qt < 2; ++qt) s[kvt][qt] = (f32x4){0.f, 0.f, 0.f, 0.f};
            #pragma unroll
            for (int kd = 0; kd < 2; ++kd)
                #pragma unroll
                for (int kvt = 0; kvt < 4; ++kvt)
                    #pragma unroll
                    for (int qt = 0; qt < 2; ++qt)
                        s[kvt][qt] = __builtin_amdgcn_mfma_f32_16x16x32_bf16(ak[kvt][kd], bq[qt][kd], s[kvt][qt], 0, 0, 0);
            if (kt == ktmax) {  // causal mask, diagonal tile only
                #pragma unroll
                for (int qt = 0; qt < 2; ++qt) {
                    int qabs = R0 + qt * 16 + l15;
                    #pragma unroll
                    for (int kvt = 0; kvt < 4; ++kvt) {
                        int kvb = k0 + kvt * 16 + quad * 4;
                        #pragma unroll
                        for (int r = 0; r < 4; ++r)
                            if (kvb + r > qabs) s[kvt][qt][r] = -INFINITY;
                    }
                }
            }
            // online softmax (exp2 domain), reduction over kv: 15 in-lane + 2 shfl
            float alpha[2];
            #pragma unroll
            for (int qt = 0; qt < 2; ++qt) {
                float vm = s[0][qt][0];
                #pragma unroll
                for (int kvt = 0; kvt < 4; ++kvt)
                    #pragma unroll
                    for (int r = 0; r < 4; ++r) vm = fmaxf(vm, s[kvt][qt][r]);
                vm = fmaxf(vm, __shfl_xor(vm, 16));
                vm = fmaxf(vm, __shfl_xor(vm, 32));
                float mn = fmaxf(m2[qt], vm * scale2);
                alpha[qt] = __builtin_amdgcn_exp2f(m2[qt] - mn);
                m2[qt] = mn;
            }
            #pragma unroll
            for (int kvt = 0; kvt < 4; ++kvt)
                #pragma unroll
                for (int qt = 0; qt < 2; ++qt)
                    #pragma unroll
                    for (int r = 0; r < 4; ++r)
                        s[kvt][qt][r] = __builtin_amdgcn_exp2f(fmaf(s[kvt][qt][r], scale2, -m2[qt]));
            // rescale accumulators
            #pragma unroll
            for (int dt = 0; dt < 4; ++dt)
                #pragma unroll
                for (int qt = 0; qt < 2; ++qt)
                    #pragma unroll
                    for (int r = 0; r < 4; ++r) o[dt][qt][r] *= alpha[qt];
            #pragma unroll
            for (int qt = 0; qt < 2; ++qt)
                #pragma unroll
                for (int r = 0; r < 4; ++r) lacc[qt][r] *= alpha[qt];
            // pack P as bf16 into wave-private LDS: P[qrow][kv]
            #pragma unroll
            for (int qt = 0; qt < 2; ++qt)
                #pragma unroll
                for (int kvt = 0; kvt < 4; ++kvt) {
                    bf16x4 w;
                    #pragma unroll
                    for (int r = 0; r < 4; ++r) w[r] = (__bf16)s[kvt][qt][r];
                    *(bf16x4*)&pw[(qt * 16 + l15) * 72 + kvt * 16 + quad * 4] = w;
                }
            // O^T += V^T . P^T ; l += ones . P^T
            #pragma unroll
            for (int qt = 0; qt < 2; ++qt)
                #pragma unroll
                for (int ks = 0; ks < 2; ++ks) {
                    bf16x8 bp = *(const bf16x8*)&pw[(qt * 16 + l15) * 72 + ks * 32 + quad * 8];
                    #pragma unroll
                    for (int dt = 0; dt < 4; ++dt)
                        o[dt][qt] = __builtin_amdgcn_mfma_f32_16x16x32_bf16(av[dt][ks], bp, o[dt][qt], 0, 0, 0);
                    lacc[qt] = __builtin_amdgcn_mfma_f32_16x16x32_bf16(ones, bp, lacc[qt], 0, 0, 0);
                }
        }
        // epilogue: O^T[d][qrow] / l -> att[b*T+qrow][h*64+d]
        #pragma unroll
        for (int qt = 0; qt < 2; ++qt) {
            float rl = __builtin_amdgcn_rcpf(lacc[qt][0]);
            int qabs = R0 + qt * 16 + l15;
            #pragma unroll
            for (int dt = 0; dt < 4; ++dt) {
                bf16x4 w;
                #pragma unroll
                for (int r = 0; r < 4; ++r) w[r] = (__bf16)(o[dt][qt][r] * rl);
                *(bf16x4*)&att[(size_t)(b * T_ + qabs) * C_ + h * 64 + dt * 16 + quad * 4] = w;
            }
        }
    }
}

// ------ out proj: att[8192,1024] x wo[1024,1024]^T + bo -> fp32 out -------
__global__ __launch_bounds__(256) void out_gemm(const u16* __restrict__ att,
                                                const u16* __restrict__ wo,
                                                const float* __restrict__ bo,
                                                float* __restrict__ out) {
    __shared__ u16 Al[128][72];
    __shared__ u16 Bl[128][72];
    int mb = blockIdx.x, nb = blockIdx.y;
    int tid = threadIdx.x, wid = tid >> 6, lane = tid & 63, l15 = lane & 15, quad = lane >> 4;
    int rowh = (wid & 1) * 64, colh = (wid >> 1) * 64;
    f32x4 acc[4][4];
    #pragma unroll
    for (int i = 0; i < 4; ++i)
        #pragma unroll
        for (int j = 0; j < 4; ++j) acc[i][j] = (f32x4){0.f, 0.f, 0.f, 0.f};
    int scol = (tid & 7) * 8, srow = tid >> 3;
    for (int k0 = 0; k0 < C_; k0 += 64) {
        #pragma unroll
        for (int cc = 0; cc < 4; ++cc) {
            int r = srow + cc * 32;
            *(u16x8*)&Al[r][scol] = *(const u16x8*)&att[(size_t)(mb * 128 + r) * C_ + k0 + scol];
            *(u16x8*)&Bl[r][scol] = *(const u16x8*)&wo[(size_t)(nb * 128 + r) * C_ + k0 + scol];
        }
        __syncthreads();
        #pragma unroll
        for (int ks = 0; ks < 2; ++ks) {
            bf16x8 af[4], bf[4];
            #pragma unroll
            for (int mt = 0; mt < 4; ++mt)
                af[mt] = *(const bf16x8*)&Al[rowh + mt * 16 + l15][ks * 32 + quad * 8];
            #pragma unroll
            for (int nt = 0; nt < 4; ++nt)
                bf[nt] = *(const bf16x8*)&Bl[colh + nt * 16 + l15][ks * 32 + quad * 8];
            #pragma unroll
            for (int mt = 0; mt < 4; ++mt)
                #pragma unroll
                for (int nt = 0; nt < 4; ++nt)
                    acc[mt][nt] = __builtin_amdgcn_mfma_f32_16x16x32_bf16(af[mt], bf[nt], acc[mt][nt], 0, 0, 0);
        }
        __syncthreads();
    }
    #pragma unroll
    for (int nt = 0; nt < 4; ++nt) {
        int n = nb * 128 + colh + nt * 16 + l15;
        float bias = bo[n];
        #pragma unroll
        for (int mt = 0; mt < 4; ++mt)
            #pragma unroll
            for (int r = 0; r < 4; ++r) {
                int m = mb * 128 + rowh + mt * 16 + quad * 4 + r;
                out[(size_t)m * C_ + n] = acc[mt][nt][r] + bias;
            }
    }
}

extern "C" void kernel_launch(void* const* d_in, const int* in_sizes, int n_in,
                              void* d_out, int out_size, void* d_ws, size_t ws_size,
                              hipStream_t stream) {
    const float* x  = (const float*)d_in[0];
    const float* Wq = (const float*)d_in[1];
    const float* Wk = (const float*)d_in[2];
    const float* Wv = (const float*)d_in[3];
    const float* Wo = (const float*)d_in[4];
    const float* bo = (const float*)d_in[5];
    float* out = (float*)d_out;
    char* ws = (char*)d_ws;
    u16* xbf  = (u16*)(ws + (size_t)0);           // 16 MB  x bf16 [8192,1024]
    u16* wt   = (u16*)(ws + ((size_t)16 << 20));  //  6 MB  W qkv [3072,1024] bf16
    u16* wobf = (u16*)(ws + ((size_t)22 << 20));  //  2 MB  Wo bf16 [1024,1024]
    u16* qb   = (u16*)(ws + ((size_t)24 << 20));  // 16 MB  q [BH,T,D]
    u16* kb   = (u16*)(ws + ((size_t)40 << 20));  // 16 MB  k [BH,T,D]
    u16* vb   = (u16*)(ws + ((size_t)56 << 20));  // 16 MB  v [BH,T,D]
    u16* vtb  = (u16*)(ws + ((size_t)72 << 20));  // 16 MB  v^T [BH,D,T]
    u16* attb = (u16*)(ws + ((size_t)88 << 20));  // 16 MB  att out [B*T,C]

    hipLaunchKernelGGL(cast_f32_bf16, dim3(BT * C_ / 1024), dim3(256), 0, stream, x, xbf);
    hipLaunchKernelGGL(cast_f32_bf16, dim3(C_ * C_ / 1024), dim3(256), 0, stream, Wo, wobf);
    hipLaunchKernelGGL(transpose_w, dim3(C_ / 64, H_, 3), dim3(256), 0, stream, Wq, Wk, Wv, wt);
    hipLaunchKernelGGL(qkv_gemm, dim3(BT / 128, 3 * C_ / 128), dim3(256), 0, stream, xbf, wt, qb, kb, vb);
    hipLaunchKernelGGL(vtrans, dim3(T_ / 64, BH), dim3(256), 0, stream, vb, vtb);
    hipLaunchKernelGGL(attn, dim3(8, BH), dim3(256), 0, stream, qb, kb, vtb, attb);
    hipLaunchKernelGGL(out_gemm, dim3(BT / 128, C_ / 128), dim3(256), 0, stream, attb, wobf, bo, out);
}